// Round 12
// baseline (707.599 us; speedup 1.0000x reference)
//
#include <hip/hip_runtime.h>

typedef unsigned short u16;
typedef unsigned int u32;
typedef unsigned long long u64;
typedef __attribute__((ext_vector_type(4))) float f32x4;
typedef __attribute__((ext_vector_type(8))) short s16x8;
typedef __attribute__((ext_vector_type(4))) int i32x4;

#define EPS 1e-5f

// ---------- helpers ----------
__device__ __forceinline__ u16 f2bf(float f) {
  unsigned u = __float_as_uint(f);
  return (u16)((u + 0x7fffu + ((u >> 16) & 1u)) >> 16);
}
__device__ __forceinline__ float sigm(float x) { return 1.0f / (1.0f + __expf(-x)); }
__device__ __forceinline__ float tanh_f(float x) {
  float e = __expf(-2.0f * fabsf(x));
  float r = (1.0f - e) / (1.0f + e);
  return copysignf(r, x);
}
__device__ __forceinline__ void gl_lds16(const void* g, void* l) {
  __builtin_amdgcn_global_load_lds(
      (const __attribute__((address_space(1))) u32*)g,
      (__attribute__((address_space(3))) u32*)l, 16, 0, 0);
}

// ---------- merged setup: weight pack + x transpose + zero ----------
// bid<1920: wcvt; 1920..2943: xtrans; 2944..3455: zero hT/cx
__global__ __launch_bounds__(256) void k_setup(
    const float* __restrict__ cw, u16* __restrict__ Wpk,
    const float* __restrict__ x, u16* __restrict__ xT,
    i32x4* __restrict__ hTz, i32x4* __restrict__ cxz) {
  const int bid = blockIdx.x, tid = threadIdx.x;
  __shared__ __align__(16) u16 ltile[256 * 72];
  if (bid < 1920) {
    // f = (tap*6+kk)*32 + of ; of = gate-ch>>4 ; element = lane*8+j
    // A[o][c]: o = of*16 + (lane&15), c = kk*32 + (lane>>4)*8 + j
    int idx = bid * 256 + tid;                 // exactly 491520
    int f = idx >> 9, r = idx & 511;
    int lane = r >> 3, j = r & 7;
    int of = f & 31, tk = f >> 5;
    int kk = tk % 6, tap = tk / 6;
    int o = (of << 4) + (lane & 15);
    int c = (kk << 5) + ((lane >> 4) << 3) + j;
    Wpk[idx] = f2bf(cw[(o * 192 + c) * 5 + tap]);
  } else if (bid < 2944) {
    // x (t,b,64,256) f32 -> xT[t*32+b][264 rows][64 ch] bf16, swizzled, halos zeroed
    int tb = bid - 1920;
    const float* src = x + tb * (64 * 256);
    for (int it = 0; it < 64; ++it) {
      int idx = it * 256 + tid;
      int c = idx >> 8, l = idx & 255;
      ltile[l * 72 + c] = f2bf(src[idx]);
    }
    __syncthreads();
    char* dst = (char*)(xT + tb * 16896);
    i32x4 z = {0, 0, 0, 0};
    for (int i = tid; i < 2112; i += 256) {    // 264 rows x 8 chunks
      int r = i >> 3, ch = i & 7;
      i32x4 v = z;
      if (r >= 2 && r < 258) v = *(const i32x4*)(ltile + (r - 2) * 72 + ch * 8);
      *(i32x4*)(dst + r * 128 + ((ch * 16) ^ ((r & 7) << 4))) = v;
    }
  } else {
    int base = (bid - 2944) * 256 + tid;       // 131072 threads
    i32x4 z = {0, 0, 0, 0};
    for (int i = base; i < 270336; i += 131072) hTz[i] = z;   // hT both buffers
    for (int i = base; i < 262144; i += 131072) cxz[i] = z;   // cx
  }
}

// ---------- fused step: 4 complete GN groups per block -> NO cross-block sync at all ----------
// grid 128: bid = (cs<<5) | b  (same-b blocks share XCD: bid%8 = b%8)
// block 512 = 8 waves (wm 2 x wl 4). Block: ch strip cs (32 hy-ch x 4 gates = M128) x FULL 256 L.
// Wave: 4 m-frags (one per gate, same 16 ch) x 4 n-frags (64 L) -> thread-local LSTM cells.
__global__ __launch_bounds__(512, 1) void k_step(
    const u16* __restrict__ Wpk, const u16* __restrict__ xT, u16* __restrict__ hT,
    const float* __restrict__ cb, const float* __restrict__ gnw, const float* __restrict__ gnb,
    float* __restrict__ cx, float* __restrict__ out, int t) {
  const int bid = blockIdx.x;
  const int b = bid & 31, cs = bid >> 5;
  const int tid = threadIdx.x, wave = tid >> 6, lane = tid & 63;
  const int wm = wave & 1, wl = wave >> 1;
  const int l15 = lane & 15, q = lane >> 4;
  const int cgrp = q << 4;

  __shared__ __align__(16) char ldsx[33792];   // 264 rows x 128 B (x, swizzled)
  __shared__ __align__(16) char ldsh[67584];   // 264 rows x 256 B (h, swizzled)
  __shared__ __align__(16) char hl[16384];     // 256 l x 64 B (32 ch bf16, 8B-slot swizzled)
  __shared__ float red[8][4][2];
  __shared__ float smu[4], srs[4];

  const u16* hTr = hT + (t & 1) * 1081344;
  u16* hTw = hT + ((t + 1) & 1) * 1081344;

  // ---- stage x(t), h(t) full-L (swizzle pre-baked in global) ----
  {
    const char* gx = (const char*)(xT + ((t << 5) + b) * 16896);
    for (int i = tid; i < 2112; i += 512) gl_lds16(gx + (i << 4), ldsx + (i << 4));
    const char* gh = (const char*)hTr + b * 67584;
    for (int i = tid; i < 4224; i += 512) gl_lds16(gh + (i << 4), ldsh + (i << 4));
  }
  asm volatile("s_waitcnt vmcnt(0)" ::: "memory");
  __syncthreads();

  // ---- K-loop: 30 chunks, A direct from L1/L2, B from LDS, no barriers ----
  f32x4 zero4 = {0.f, 0.f, 0.f, 0.f};
  f32x4 acc[4][4];
  #pragma unroll
  for (int g = 0; g < 4; ++g)
    #pragma unroll
    for (int ni = 0; ni < 4; ++ni) acc[g][ni] = zero4;

  const s16x8* Wv = (const s16x8*)Wpk;
  for (int tap = 0; tap < 5; ++tap) {
    #pragma unroll
    for (int kk = 0; kk < 6; ++kk) {
      const int cc = tap * 6 + kk;
      s16x8 av[4], bv[4];
      #pragma unroll
      for (int g = 0; g < 4; ++g) {
        const int of = (g << 3) + (cs << 1) + wm;
        av[g] = Wv[(((cc << 5) + of) << 6) + lane];
      }
      #pragma unroll
      for (int ni = 0; ni < 4; ++ni) {
        const int rr = (wl << 6) + (ni << 4) + l15 + tap;
        const int sw = (rr & 7) << 4;
        bv[ni] = (kk < 2)
          ? *(const s16x8*)(ldsx + (rr << 7) + (((kk << 6) + cgrp) ^ sw))
          : *(const s16x8*)(ldsh + (rr << 8) + ((((kk - 2) << 6) + cgrp) ^ sw));
      }
      #pragma unroll
      for (int g = 0; g < 4; ++g)
        #pragma unroll
        for (int ni = 0; ni < 4; ++ni)
          acc[g][ni] = __builtin_amdgcn_mfma_f32_16x16x32_bf16(av[g], bv[ni], acc[g][ni], 0, 0, 0);
    }
  }

  // ---- +bias, per-gate stats over the FULL group (32 ch x 256 L, block-local) ----
  const int chq = (cs << 5) + (wm << 4) + (q << 2);   // hy-ch base for r=0
  float sum4[4], sq4[4];
  #pragma unroll
  for (int g = 0; g < 4; ++g) {
    const f32x4 bias = *(const f32x4*)(cb + (g << 7) + chq);
    sum4[g] = 0.f; sq4[g] = 0.f;
    #pragma unroll
    for (int ni = 0; ni < 4; ++ni)
      #pragma unroll
      for (int r = 0; r < 4; ++r) {
        float v = acc[g][ni][r] + bias[r];
        acc[g][ni][r] = v;
        sum4[g] += v; sq4[g] += v * v;
      }
  }
  // preload pointwise params + cx (hides L2 latency under the reduction)
  f32x4 w4[4], b4[4];
  float cxv[4][4];
  #pragma unroll
  for (int g = 0; g < 4; ++g) {
    w4[g] = *(const f32x4*)(gnw + (g << 7) + chq);
    b4[g] = *(const f32x4*)(gnb + (g << 7) + chq);
  }
  #pragma unroll
  for (int ni = 0; ni < 4; ++ni) {
    const int l = (wl << 6) + (ni << 4) + l15;
    #pragma unroll
    for (int r = 0; r < 4; ++r)
      cxv[ni][r] = cx[(b << 15) + ((chq + r) << 8) + l];
  }
  #pragma unroll
  for (int off = 1; off < 64; off <<= 1) {
    #pragma unroll
    for (int g = 0; g < 4; ++g) {
      sum4[g] += __shfl_xor(sum4[g], off);
      sq4[g]  += __shfl_xor(sq4[g], off);
    }
  }
  if (lane == 0) {
    #pragma unroll
    for (int g = 0; g < 4; ++g) { red[wave][g][0] = sum4[g]; red[wave][g][1] = sq4[g]; }
  }
  __syncthreads();
  if (tid < 4) {   // fixed-order 8-wave sum -> deterministic
    float s = 0.f, qv = 0.f;
    #pragma unroll
    for (int w = 0; w < 8; ++w) { s += red[w][tid][0]; qv += red[w][tid][1]; }
    const float inv = 1.0f / 8192.0f;
    float m = s * inv;
    smu[tid] = m;
    srs[tid] = rsqrtf(qv * inv - m * m + EPS);
  }
  __syncthreads();

  // ---- GN apply + LSTM pointwise (thread-local, all 4 gates in registers) ----
  const float mu0 = smu[0], mu1 = smu[1], mu2 = smu[2], mu3 = smu[3];
  const float rs0 = srs[0], rs1 = srs[1], rs2 = srs[2], rs3 = srs[3];
  float* outp = out + (((t << 5) + b) << 15);
  #pragma unroll
  for (int ni = 0; ni < 4; ++ni) {
    const int l = (wl << 6) + (ni << 4) + l15;
    u16 hp[4];
    #pragma unroll
    for (int r = 0; r < 4; ++r) {
      const int c = chq + r;
      float vi = (acc[0][ni][r] - mu0) * rs0 * w4[0][r] + b4[0][r];
      float vf = (acc[1][ni][r] - mu1) * rs1 * w4[1][r] + b4[1][r];
      float vg = (acc[2][ni][r] - mu2) * rs2 * w4[2][r] + b4[2][r];
      float vo = (acc[3][ni][r] - mu3) * rs3 * w4[3][r] + b4[3][r];
      float cyv = sigm(vf) * cxv[ni][r] + sigm(vi) * tanh_f(vg);
      float hyv = sigm(vo) * tanh_f(cyv);
      const int ci = (c << 8) + l;
      cx[(b << 15) + ci] = cyv;
      outp[ci] = hyv;
      hp[r] = f2bf(hyv);
      if (t == 31) {
        out[33554432 + (b << 15) + ci] = hyv;   // final hy
        out[34603008 + (b << 15) + ci] = cyv;   // final cy
      }
    }
    // 8B slot store, slot-swizzled by (l&3) at 16B granularity
    *(u64*)(hl + (l << 6) + (((wm << 5) + (q << 3)) ^ ((l & 3) << 4))) =
        *(const u64*)hp;
  }
  __syncthreads();

  // ---- cooperative transposed h write: strip cs, full 256 L -> hTw ----
  #pragma unroll
  for (int i = tid; i < 1024; i += 512) {
    const int ll = i >> 2, k = i & 3;
    const int row = ll + 2;
    i32x4 v = *(const i32x4*)(hl + (ll << 6) + ((k << 4) ^ ((ll & 3) << 4)));
    char* dst = (char*)hTw + b * 67584 + (row << 8) +
                ((((cs << 2) + k) << 4) ^ ((row & 7) << 4));
    *(i32x4*)dst = v;
  }
}

// ---------- launch ----------
extern "C" void kernel_launch(void* const* d_in, const int* in_sizes, int n_in,
                              void* d_out, int out_size, void* d_ws, size_t ws_size,
                              hipStream_t stream) {
  const float* x  = (const float*)d_in[0];
  const float* cw = (const float*)d_in[1];
  const float* cb = (const float*)d_in[2];
  const float* gw = (const float*)d_in[3];
  const float* gb = (const float*)d_in[4];
  float* out = (float*)d_out;
  char* ws = (char*)d_ws;

  u16*   Wpk = (u16*)(ws);                 //     983,040 B
  u16*   xT  = (u16*)(ws + 983040);        //  34,603,008 B
  u16*   hT  = (u16*)(ws + 35586048);      //   4,325,376 B (ping-pong)
  float* cx  = (float*)(ws + 39911424);    //   4,194,304 B  (~44.1 MB)

  k_setup<<<3456, 256, 0, stream>>>(cw, Wpk, x, xT, (i32x4*)hT, (i32x4*)cx);
  for (int t = 0; t < 32; ++t)
    k_step<<<128, 512, 0, stream>>>(Wpk, xT, hT, cb, gw, gb, cx, out, t);
}